// Round 1
// baseline (784.295 us; speedup 1.0000x reference)
//
#include <hip/hip_runtime.h>
#include <hip/hip_bf16.h>
#include <cstdint>

// Shapes: B=4, S=4096, E=2048, H=16, D=128 -> 16384 independent tokens.
// qkv = x @ W_qkv (16384x2048x6144); per-token 16x16 head-softmax mix;
// out = attn @ W_out + b_out (16384x2048x2048).

#define TOKENS 16384
#define EMB    2048
#define NQKV   6144

typedef __bf16 bf16x8_t __attribute__((ext_vector_type(8)));
typedef float  f32x4_t  __attribute__((ext_vector_type(4)));

// global -> LDS direct copy, 16B per lane. LDS dest must be wave-uniform base
// (HW writes base + lane*16). AS casts routed through uintptr_t (low 32 bits of
// a generic LDS pointer are the LDS offset).
#define GLOAD16(gsrc, ldst)                                                    \
  __builtin_amdgcn_global_load_lds(                                            \
      (const __attribute__((address_space(1))) void*)(uintptr_t)(gsrc),        \
      (__attribute__((address_space(3))) void*)(uint32_t)(uintptr_t)(ldst),    \
      16, 0, 0)

static __device__ __forceinline__ unsigned short f32_to_bf16_bits(float f) {
  union { float f; uint32_t u; } x; x.f = f;
  uint32_t u = x.u;
  u += 0x7fffu + ((u >> 16) & 1u);   // round-to-nearest-even
  return (unsigned short)(u >> 16);
}

// ---------------------------------------------------------------- converts
__global__ __launch_bounds__(256) void cvt_f32_bf16(
    const float4* __restrict__ in, ushort4* __restrict__ out, int n4) {
  const int stride = gridDim.x * blockDim.x;
  for (int i = blockIdx.x * blockDim.x + threadIdx.x; i < n4; i += stride) {
    float4 v = in[i];
    ushort4 o;
    o.x = f32_to_bf16_bits(v.x);
    o.y = f32_to_bf16_bits(v.y);
    o.z = f32_to_bf16_bits(v.z);
    o.w = f32_to_bf16_bits(v.w);
    out[i] = o;
  }
}

// transpose R x C f32 -> C x R bf16 (so GEMM B-operand is k-contiguous)
__global__ __launch_bounds__(256) void transpose_cvt(
    const float* __restrict__ in, unsigned short* __restrict__ out, int R, int C) {
  __shared__ float tile[32][33];
  const int bx = blockIdx.x * 32;   // col block (C)
  const int by = blockIdx.y * 32;   // row block (R)
  const int tx = threadIdx.x;       // 0..31
  const int ty = threadIdx.y;       // 0..7
#pragma unroll
  for (int j = 0; j < 32; j += 8)
    tile[ty + j][tx] = in[(size_t)(by + ty + j) * C + bx + tx];
  __syncthreads();
#pragma unroll
  for (int j = 0; j < 32; j += 8)
    out[(size_t)(bx + ty + j) * R + by + tx] = f32_to_bf16_bits(tile[tx][ty + j]);
}

// ---------------------------------------------------------------- GEMM
// C[M,N] = A[M,K] * BT[N,K]^T, bf16 in, fp32 acc. 128x128 tile, BK=64,
// 4 waves (2x2), each wave 64x64 via 4x4 mfma_f32_16x16x32_bf16 frags.
template <bool OUT_BF16>
__global__ __launch_bounds__(256, 2) void gemm_bt(
    const unsigned short* __restrict__ A,   // M x K   bf16
    const unsigned short* __restrict__ BT,  // N x K   bf16
    unsigned short* __restrict__ Cb,        // M x N   bf16  (OUT_BF16)
    float* __restrict__ Cf,                 // M x N   f32   (!OUT_BF16)
    const float* __restrict__ bias,         // N or null
    int M, int N, int K) {
  constexpr int BM = 128, BN = 128, BK = 64;
  __shared__ __align__(16) unsigned short sA[BM * BK];
  __shared__ __align__(16) unsigned short sB[BN * BK];

  const int nbx = N / BN;
  const int nwg = gridDim.x;                       // % 8 == 0 for our launches
  const int bid = blockIdx.x;
  const int swz = (bid & 7) * (nwg >> 3) + (bid >> 3);  // bijective XCD swizzle
  const int by = swz / nbx;
  const int bx = swz % nbx;

  const int t    = threadIdx.x;
  const int lane = t & 63;
  const int lr   = lane & 15;          // frag row (A) / col (B) / col (C)
  const int lk   = (lane >> 4) * 8;    // frag k offset
  const int wm   = ((t >> 7) & 1) * 64;
  const int wn   = ((t >> 6) & 1) * 64;

  const unsigned short* aSrc = A  + (size_t)by * BM * K;
  const unsigned short* bSrc = BT + (size_t)bx * BN * K;

  auto stage = [&](int k0) {
    const int wbase = (t & 192) * 16;  // wave-uniform byte base within an issue
#pragma unroll
    for (int i = 0; i < 4; ++i) {      // A tile: 128x64 bf16 = 16 KiB
      const int idx = i * 256 + t;
      const int row = idx >> 3;
      const int kel = (idx & 7) << 3;
      GLOAD16(aSrc + (size_t)row * K + k0 + kel, (char*)sA + i * 4096 + wbase);
    }
#pragma unroll
    for (int i = 0; i < 4; ++i) {      // B tile: 128x64 bf16 = 16 KiB
      const int idx = i * 256 + t;
      const int row = idx >> 3;
      const int kel = (idx & 7) << 3;
      GLOAD16(bSrc + (size_t)row * K + k0 + kel, (char*)sB + i * 4096 + wbase);
    }
  };

  f32x4_t acc[4][4] = {};

  stage(0);
  const int nkt = K / BK;
  for (int kt = 0; kt < nkt; ++kt) {
    __syncthreads();                   // compiler drains vmcnt(0) before barrier
#pragma unroll
    for (int ks = 0; ks < 2; ++ks) {
      bf16x8_t av[4], bv[4];
#pragma unroll
      for (int mf = 0; mf < 4; ++mf)
        av[mf] = *(const bf16x8_t*)(sA + (wm + mf * 16 + lr) * BK + ks * 32 + lk);
#pragma unroll
      for (int nf = 0; nf < 4; ++nf)
        bv[nf] = *(const bf16x8_t*)(sB + (wn + nf * 16 + lr) * BK + ks * 32 + lk);
#pragma unroll
      for (int mf = 0; mf < 4; ++mf)
#pragma unroll
        for (int nf = 0; nf < 4; ++nf)
          acc[mf][nf] = __builtin_amdgcn_mfma_f32_16x16x32_bf16(
              av[mf], bv[nf], acc[mf][nf], 0, 0, 0);
    }
    __syncthreads();
    if (kt + 1 < nkt) stage((kt + 1) * BK);
  }

  // C/D frag map (m89-verified): col = lane&15, row = (lane>>4)*4 + j
  const int rbase = by * BM + wm + (lane >> 4) * 4;
  const int cbase = bx * BN + wn + lr;
#pragma unroll
  for (int mf = 0; mf < 4; ++mf) {
#pragma unroll
    for (int nf = 0; nf < 4; ++nf) {
      const int col = cbase + nf * 16;
#pragma unroll
      for (int j = 0; j < 4; ++j) {
        const size_t off = (size_t)(rbase + mf * 16 + j) * N + col;
        if constexpr (OUT_BF16) {
          Cb[off] = f32_to_bf16_bits(acc[mf][nf][j]);
        } else {
          Cf[off] = acc[mf][nf][j] + bias[col];
        }
      }
    }
  }
}

// ---------------------------------------------------------------- attention
// One block per token. qkv row = [Q(16x128) | K(16x128) | V(16x128)] bf16.
// scores[h][H] = q_h . k_H / sqrt(128); softmax over H; attn_h = sum_H w*v_H.
__global__ __launch_bounds__(256) void attn_heads(
    const unsigned short* __restrict__ qkv,  // [T][3*2048] bf16
    unsigned short* __restrict__ attn) {     // [T][2048]   bf16
  __shared__ __align__(16) unsigned short sQKV[NQKV];  // 12 KiB
  __shared__ float sW[16][16];

  const int t = threadIdx.x;
  const size_t qbase = (size_t)blockIdx.x * NQKV;

  // load 768 x 16B chunks; K region (chunks 256..511) XOR-swizzled per row
  // to break the stride-256B bank conflict on the score reads.
  const uint4* g = (const uint4*)(qkv + qbase);
  uint4* l = (uint4*)sQKV;
#pragma unroll
  for (int i = 0; i < 3; ++i) {
    const int idx = i * 256 + t;
    int dst = idx;
    if (idx >= 256 && idx < 512) {
      const int r = (idx - 256) >> 4;  // K head row 0..15
      const int c = idx & 15;
      dst = 256 + r * 16 + (c ^ (r & 7));
    }
    l[dst] = g[idx];
  }
  __syncthreads();

  // scores: thread t -> (h = t>>4, H = t&15)
  const int h = t >> 4;
  const int H = t & 15;
  const bf16x8_t* q8 = (const bf16x8_t*)sQKV + h * 16;
  const bf16x8_t* k8 = (const bf16x8_t*)sQKV + 256;
  float s = 0.f;
#pragma unroll
  for (int d8 = 0; d8 < 16; ++d8) {
    bf16x8_t qv = q8[d8];
    bf16x8_t kv = k8[H * 16 + (d8 ^ (H & 7))];  // read with same swizzle
#pragma unroll
    for (int j = 0; j < 8; ++j)
      s = fmaf((float)qv[j], (float)kv[j], s);
  }
  s *= 0.08838834764831843f;  // 1/sqrt(128)

  // softmax across the 16-lane row group
  float mx = s;
#pragma unroll
  for (int o = 8; o; o >>= 1) mx = fmaxf(mx, __shfl_xor(mx, o));
  const float e = __expf(s - mx);
  float sum = e;
#pragma unroll
  for (int o = 8; o; o >>= 1) sum += __shfl_xor(sum, o);
  sW[h][H] = e / sum;
  __syncthreads();

  // PV: thread t -> head h (t>>4), 8 consecutive d at d0 = (t&15)*8
  const int d0c = t & 15;
  const bf16x8_t* v8 = (const bf16x8_t*)sQKV + 512;
  float accv[8] = {};
#pragma unroll
  for (int j = 0; j < 16; ++j) {
    const float w = sW[h][j];
    const bf16x8_t vv = v8[j * 16 + d0c];
#pragma unroll
    for (int jj = 0; jj < 8; ++jj)
      accv[jj] = fmaf(w, (float)vv[jj], accv[jj]);
  }
  bf16x8_t o;
#pragma unroll
  for (int jj = 0; jj < 8; ++jj) o[jj] = (__bf16)accv[jj];
  *(bf16x8_t*)(attn + (size_t)blockIdx.x * EMB + h * 128 + d0c * 8) = o;
}

// ---------------------------------------------------------------- launch
extern "C" void kernel_launch(void* const* d_in, const int* in_sizes, int n_in,
                              void* d_out, int out_size, void* d_ws, size_t ws_size,
                              hipStream_t stream) {
  const float* x     = (const float*)d_in[0];  // [4,4096,2048]
  const float* Wqkv  = (const float*)d_in[1];  // [2048,6144]
  const float* Wout  = (const float*)d_in[2];  // [2048,2048]
  const float* bout  = (const float*)d_in[3];  // [2048]
  float* out = (float*)d_out;                  // [4,4096,2048]

  // workspace layout (bf16 elements); total = 369,098,752 bytes
  unsigned short* xb    = (unsigned short*)d_ws;          // 33,554,432
  unsigned short* wqkvT = xb    + (size_t)33554432;       // 12,582,912 (6144x2048)
  unsigned short* woutT = wqkvT + (size_t)12582912;       //  4,194,304 (2048x2048)
  unsigned short* qkv   = woutT + (size_t)4194304;        // 100,663,296
  unsigned short* attn  = qkv   + (size_t)100663296;      // 33,554,432

  // 1. x -> bf16
  cvt_f32_bf16<<<2048, 256, 0, stream>>>((const float4*)x, (ushort4*)xb, 33554432 / 4);
  // 2. W_qkv^T, W_out^T -> bf16 (N x K layout for the GEMM B-operand)
  transpose_cvt<<<dim3(6144 / 32, 2048 / 32), dim3(32, 8), 0, stream>>>(Wqkv, wqkvT, 2048, 6144);
  transpose_cvt<<<dim3(2048 / 32, 2048 / 32), dim3(32, 8), 0, stream>>>(Wout, woutT, 2048, 2048);
  // 3. qkv = x @ W_qkv   (grid = 128*48 = 6144 blocks, %8==0)
  gemm_bt<true><<<(16384 / 128) * (6144 / 128), 256, 0, stream>>>(
      xb, wqkvT, qkv, nullptr, nullptr, 16384, 6144, 2048);
  // 4. per-token head mixing
  attn_heads<<<TOKENS, 256, 0, stream>>>(qkv, attn);
  // 5. out = attn @ W_out + b_out  (grid = 128*16 = 2048 blocks, %8==0)
  gemm_bt<false><<<(16384 / 128) * (2048 / 128), 256, 0, stream>>>(
      attn, woutT, nullptr, out, bout, 16384, 2048, 2048);
}

// Round 2
// 621.354 us; speedup vs baseline: 1.2622x; 1.2622x over previous
//
#include <hip/hip_runtime.h>
#include <hip/hip_bf16.h>
#include <cstdint>

// B=4, S=4096, E=2048, H=16, D=128 -> 16384 independent tokens.
// qkv = x @ W_qkv (16384x2048x6144); per-token 16x16 head mix;
// out = attn @ W_out + b_out (16384x2048x2048).

#define TOKENS 16384
#define EMB    2048
#define NQKV   6144

typedef __bf16 bf16x8_t __attribute__((ext_vector_type(8)));
typedef float  f32x4_t  __attribute__((ext_vector_type(4)));

#define GLOAD16(gsrc, ldst)                                                    \
  __builtin_amdgcn_global_load_lds(                                            \
      (const __attribute__((address_space(1))) void*)(uintptr_t)(gsrc),        \
      (__attribute__((address_space(3))) void*)(uint32_t)(uintptr_t)(ldst),    \
      16, 0, 0)

static __device__ __forceinline__ unsigned short f32_to_bf16_bits(float f) {
  union { float f; uint32_t u; } x; x.f = f;
  uint32_t u = x.u;
  u += 0x7fffu + ((u >> 16) & 1u);   // round-to-nearest-even
  return (unsigned short)(u >> 16);
}

// ---------------------------------------------------------------- converts
__global__ __launch_bounds__(256) void cvt_f32_bf16(
    const float4* __restrict__ in, ushort4* __restrict__ out, int n4) {
  const int stride = gridDim.x * blockDim.x;
  for (int i = blockIdx.x * blockDim.x + threadIdx.x; i < n4; i += stride) {
    float4 v = in[i];
    ushort4 o;
    o.x = f32_to_bf16_bits(v.x);
    o.y = f32_to_bf16_bits(v.y);
    o.z = f32_to_bf16_bits(v.z);
    o.w = f32_to_bf16_bits(v.w);
    out[i] = o;
  }
}

// transpose R x C f32 -> C x R bf16
__global__ __launch_bounds__(256) void transpose_cvt(
    const float* __restrict__ in, unsigned short* __restrict__ out, int R, int C) {
  __shared__ float tile[32][33];
  const int bx = blockIdx.x * 32;
  const int by = blockIdx.y * 32;
  const int tx = threadIdx.x;
  const int ty = threadIdx.y;
#pragma unroll
  for (int j = 0; j < 32; j += 8)
    tile[ty + j][tx] = in[(size_t)(by + ty + j) * C + bx + tx];
  __syncthreads();
#pragma unroll
  for (int j = 0; j < 32; j += 8)
    out[(size_t)(bx + ty + j) * R + by + tx] = f32_to_bf16_bits(tile[tx][ty + j]);
}

// ---------------------------------------------------------------- GEMM
// 256x256 tile, BK=64, 8 waves (2M x 4N), 8-phase schedule (T2+T3+T4+T5).
// C = A[M,K] * BT[N,K]^T. K fixed at 2048.
template <bool OUT_BF16>
__global__ __launch_bounds__(512, 1) void gemm_bt(
    const unsigned short* __restrict__ A,
    const unsigned short* __restrict__ BT,
    unsigned short* __restrict__ Cb,
    float* __restrict__ Cf,
    const float* __restrict__ bias,
    int M, int N) {
  constexpr int K = 2048;
  constexpr int BK = 64;
  constexpr int NKT = K / BK;          // 32
  __shared__ __align__(16) char lds[131072];  // [2 bufs][A 32KB | B 32KB]

  const int nbx = N / 256;
  const int nwg = gridDim.x;           // % 8 == 0
  const int bid = blockIdx.x;
  const int swzb = (bid & 7) * (nwg >> 3) + (bid >> 3);
  const int by = swzb / nbx;
  const int bx = swzb % nbx;

  const int t    = threadIdx.x;
  const int lane = t & 63;
  const int wid  = t >> 6;             // 0..7
  const int wr   = wid >> 2;           // 0..1 (M)
  const int wc   = wid & 3;            // 0..3 (N)
  const int lr   = lane & 15;
  const int g    = lane >> 4;          // 0..3

  const unsigned short* aSrc = A  + (size_t)by * 256 * K;
  const unsigned short* bSrc = BT + (size_t)bx * 256 * K;

  // ---- staging source offsets (inverse-swizzled global, linear LDS dest)
  // physical chunk c = i*512 + t within a 16KB half-tile; lo = swz(c*16).
  int aoff[2], boff[2];
#pragma unroll
  for (int i = 0; i < 2; ++i) {
    const int p   = (i * 512 + t) * 16;
    const int lo  = p ^ (((p >> 7) & 7) << 4);
    const int rih = lo >> 7;           // row in half, 0..127
    const int kbe = (lo & 127) >> 1;   // k element within BK
    aoff[i] = (((rih >> 6) << 7) + (rih & 63)) * K + kbe;  // +h*64*K at use
    boff[i] = (((rih >> 5) << 6) + (rih & 31)) * K + kbe;  // +h*32*K at use
  }
  const int ldst = wid << 10;          // wave-uniform 1KB slice

  auto stageA = [&](int h, int k0, char* bufA) {
#pragma unroll
    for (int i = 0; i < 2; ++i)
      GLOAD16(aSrc + aoff[i] + h * (64 * K) + k0, bufA + h * 16384 + i * 8192 + ldst);
  };
  auto stageB = [&](int h, int k0, char* bufB) {
#pragma unroll
    for (int i = 0; i < 2; ++i)
      GLOAD16(bSrc + boff[i] + h * (32 * K) + k0, bufB + h * 16384 + i * 8192 + ldst);
  };

  // ---- swizzled ds_read addresses
  const int sw   = (lr & 7) << 4;
  const int col0 = (g * 16) ^ sw;            // ks=0 slot
  const int col1 = (64 + g * 16) ^ sw;       // ks=1 slot
  const int aRow = (wr * 64 + lr) * 128;     // + q*16384 + m2*2048
  const int bRow = (wc * 32 + lr) * 128;     // + (nf>>1)*16384 + (nf&1)*2048

  f32x4_t acc[8][4] = {};
  bf16x8_t av[4][2];   // current A quadrant (q), [m2][ks]
  bf16x8_t bv[4][2];   // all B frags of current K-tile, [nf][ks]

#define LDA(bufA, q)                                                           \
  {                                                                            \
    const char* _b = (bufA) + (q) * 16384 + aRow;                              \
    _Pragma("unroll") for (int m2 = 0; m2 < 4; ++m2) {                         \
      av[m2][0] = *(const bf16x8_t*)(_b + m2 * 2048 + col0);                   \
      av[m2][1] = *(const bf16x8_t*)(_b + m2 * 2048 + col1);                   \
    }                                                                          \
  }
#define LDB(bufB, pair)                                                        \
  {                                                                            \
    _Pragma("unroll") for (int e = 0; e < 2; ++e) {                            \
      const int nf = (pair) * 2 + e;                                           \
      const char* _b = (bufB) + (nf >> 1) * 16384 + (nf & 1) * 2048 + bRow;    \
      bv[nf][0] = *(const bf16x8_t*)(_b + col0);                               \
      bv[nf][1] = *(const bf16x8_t*)(_b + col1);                               \
    }                                                                          \
  }
#define MFMA16(q, pair)                                                        \
  _Pragma("unroll") for (int m2 = 0; m2 < 4; ++m2)                             \
  _Pragma("unroll") for (int e = 0; e < 2; ++e)                                \
  _Pragma("unroll") for (int ks = 0; ks < 2; ++ks)                             \
    acc[(q) * 4 + m2][(pair) * 2 + e] = __builtin_amdgcn_mfma_f32_16x16x32_bf16( \
        av[m2][ks], bv[(pair) * 2 + e][ks], acc[(q) * 4 + m2][(pair) * 2 + e], 0, 0, 0);

#define PHASE_TAIL                                                             \
  __builtin_amdgcn_s_barrier();                                                \
  asm volatile("s_waitcnt lgkmcnt(0)" ::: "memory");                           \
  __builtin_amdgcn_sched_barrier(0);

#define PHASE_END                                                              \
  __builtin_amdgcn_s_setprio(0);                                               \
  __builtin_amdgcn_sched_barrier(0);                                           \
  __builtin_amdgcn_s_barrier();

  // ---- prologue: K-tile 0 (buf0) fully + A-h0/B-h1 of K-tile 1 (buf1)
  {
    char* b0 = lds;
    char* b0B = lds + 32768;
    char* b1 = lds + 65536;
    char* b1B = b1 + 32768;
    stageA(0, 0, b0);
    stageB(1, 0, b0B);
    stageA(1, 0, b0);
    stageB(0, 0, b0B);
    stageA(0, BK, b1);
    stageB(1, BK, b1B);
    asm volatile("s_waitcnt vmcnt(4)" ::: "memory");  // K-tile 0 landed
    __builtin_amdgcn_s_barrier();
  }

  // ---- main loop: 4 phases per K-tile; vmcnt wait only at phase 4
  for (int kt = 0; kt < NKT; ++kt) {
    char* cA = lds + (kt & 1) * 65536;
    char* cB = cA + 32768;
    char* nA = lds + ((kt + 1) & 1) * 65536;
    char* nB = nA + 32768;
    const int k1 = (kt + 1) * BK;
    const int k2 = (kt + 2) * BK;
    const bool s1 = (kt + 1) < NKT;
    const bool s2 = (kt + 2) < NKT;

    // P1: read A(q0)+B(n0-1); stage A-h1(kt+1); mfma (q0, n0-1)
    LDA(cA, 0);
    LDB(cB, 0);
    if (s1) stageA(1, k1, nA);
    PHASE_TAIL
    __builtin_amdgcn_s_setprio(1);
    MFMA16(0, 0);
    PHASE_END

    // P2: read B(n2-3); stage B-h0(kt+1); mfma (q0, n2-3)
    LDB(cB, 1);
    if (s1) stageB(0, k1, nB);
    PHASE_TAIL
    __builtin_amdgcn_s_setprio(1);
    MFMA16(0, 1);
    PHASE_END

    // P3: read A(q1); stage A-h0(kt+2) into CURRENT buf; mfma (q1, n2-3)
    LDA(cA, 1);
    if (s2) stageA(0, k2, cA);
    PHASE_TAIL
    __builtin_amdgcn_s_setprio(1);
    MFMA16(1, 1);
    PHASE_END

    // P4: stage B-h1(kt+2); counted vmcnt; mfma (q1, n0-1)
    if (s2) stageB(1, k2, cB);
    if (s2) { asm volatile("s_waitcnt vmcnt(4)" ::: "memory"); }
    else    { asm volatile("s_waitcnt vmcnt(0)" ::: "memory"); }
    PHASE_TAIL
    __builtin_amdgcn_s_setprio(1);
    MFMA16(1, 0);
    PHASE_END
  }

  // ---- epilogue: C/D map col=lane&15, row=(lane>>4)*4+j
  const int rbase = by * 256 + wr * 128 + g * 4;
  const int cbase = bx * 256 + wc * 64 + lr;
#pragma unroll
  for (int m = 0; m < 8; ++m) {
#pragma unroll
    for (int nf = 0; nf < 4; ++nf) {
      const int col = cbase + nf * 16;
#pragma unroll
      for (int j = 0; j < 4; ++j) {
        const size_t off = (size_t)(rbase + (m >> 2) * 64 + (m & 3) * 16 + j) * N + col;
        if constexpr (OUT_BF16) {
          Cb[off] = f32_to_bf16_bits(acc[m][nf][j]);
        } else {
          Cf[off] = acc[m][nf][j] + bias[col];
        }
      }
    }
  }
#undef LDA
#undef LDB
#undef MFMA16
#undef PHASE_TAIL
#undef PHASE_END
}

// ---------------------------------------------------------------- attention
__global__ __launch_bounds__(256) void attn_heads(
    const unsigned short* __restrict__ qkv,  // [T][6144] bf16
    unsigned short* __restrict__ attn) {     // [T][2048] bf16
  __shared__ __align__(16) unsigned short sQKV[NQKV];
  __shared__ float sW[16][16];

  const int t = threadIdx.x;
  const size_t qbase = (size_t)blockIdx.x * NQKV;

  const uint4* gp = (const uint4*)(qkv + qbase);
  uint4* l = (uint4*)sQKV;
#pragma unroll
  for (int i = 0; i < 3; ++i) {
    const int idx = i * 256 + t;
    int dst = idx;
    if (idx >= 256 && idx < 512) {
      const int r = (idx - 256) >> 4;
      const int c = idx & 15;
      dst = 256 + r * 16 + (c ^ (r & 7));
    }
    l[dst] = gp[idx];
  }
  __syncthreads();

  const int h = t >> 4;
  const int H = t & 15;
  const bf16x8_t* q8 = (const bf16x8_t*)sQKV + h * 16;
  const bf16x8_t* k8 = (const bf16x8_t*)sQKV + 256;
  float s = 0.f;
#pragma unroll
  for (int d8 = 0; d8 < 16; ++d8) {
    bf16x8_t qv = q8[d8];
    bf16x8_t kv = k8[H * 16 + (d8 ^ (H & 7))];
#pragma unroll
    for (int j = 0; j < 8; ++j)
      s = fmaf((float)qv[j], (float)kv[j], s);
  }
  s *= 0.08838834764831843f;

  float mx = s;
#pragma unroll
  for (int o = 8; o; o >>= 1) mx = fmaxf(mx, __shfl_xor(mx, o));
  const float e = __expf(s - mx);
  float sum = e;
#pragma unroll
  for (int o = 8; o; o >>= 1) sum += __shfl_xor(sum, o);
  sW[h][H] = e / sum;
  __syncthreads();

  const int d0c = t & 15;
  const bf16x8_t* v8 = (const bf16x8_t*)sQKV + 512;
  float accv[8] = {};
#pragma unroll
  for (int j = 0; j < 16; ++j) {
    const float w = sW[h][j];
    const bf16x8_t vv = v8[j * 16 + d0c];
#pragma unroll
    for (int jj = 0; jj < 8; ++jj)
      accv[jj] = fmaf(w, (float)vv[jj], accv[jj]);
  }
  bf16x8_t o;
#pragma unroll
  for (int jj = 0; jj < 8; ++jj) o[jj] = (__bf16)accv[jj];
  *(bf16x8_t*)(attn + (size_t)blockIdx.x * EMB + h * 128 + d0c * 8) = o;
}

// ---------------------------------------------------------------- launch
extern "C" void kernel_launch(void* const* d_in, const int* in_sizes, int n_in,
                              void* d_out, int out_size, void* d_ws, size_t ws_size,
                              hipStream_t stream) {
  const float* x    = (const float*)d_in[0];
  const float* Wqkv = (const float*)d_in[1];
  const float* Wout = (const float*)d_in[2];
  const float* bout = (const float*)d_in[3];
  float* out = (float*)d_out;

  unsigned short* xb    = (unsigned short*)d_ws;          // 33,554,432
  unsigned short* wqkvT = xb    + (size_t)33554432;       // 12,582,912
  unsigned short* woutT = wqkvT + (size_t)12582912;       //  4,194,304
  unsigned short* qkv   = woutT + (size_t)4194304;        // 100,663,296
  unsigned short* attn  = qkv   + (size_t)100663296;      // 33,554,432

  cvt_f32_bf16<<<2048, 256, 0, stream>>>((const float4*)x, (ushort4*)xb, 33554432 / 4);
  transpose_cvt<<<dim3(6144 / 32, 2048 / 32), dim3(32, 8), 0, stream>>>(Wqkv, wqkvT, 2048, 6144);
  transpose_cvt<<<dim3(2048 / 32, 2048 / 32), dim3(32, 8), 0, stream>>>(Wout, woutT, 2048, 2048);
  // qkv = x @ W_qkv : grid 64*24 = 1536 (%8==0)
  gemm_bt<true><<<(16384 / 256) * (6144 / 256), 512, 0, stream>>>(
      xb, wqkvT, qkv, nullptr, nullptr, 16384, 6144);
  attn_heads<<<TOKENS, 256, 0, stream>>>(qkv, attn);
  // out = attn @ W_out + b_out : grid 64*8 = 512 (%8==0)
  gemm_bt<false><<<(16384 / 256) * (2048 / 256), 512, 0, stream>>>(
      attn, woutT, nullptr, out, bout, 16384, 2048);
}